// Round 8
// baseline (33.948 us; speedup 1.0000x reference)
//
#include <hip/hip_runtime.h>

#define BATCH 4
#define NPTS 8192
#define CLOUD_PTS (BATCH * NPTS)        // 32768 points per cloud
#define TOTAL_ROWS (2 * BATCH * NPTS)   // 65536 rows (dir0 + dir1)
#define NCHUNK 4                        // col chunks per row (2048 cols each)

typedef __attribute__((ext_vector_type(8))) short bf16x8;
typedef __attribute__((ext_vector_type(16))) float f32x16;

__device__ __forceinline__ unsigned short bf16rn(float f) {
    unsigned u = __float_as_uint(f);
    return (unsigned short)((u + 0x7FFFu + ((u >> 16) & 1u)) >> 16);
}
__device__ __forceinline__ float bf2f(unsigned short h) {
    return __uint_as_float(((unsigned)h) << 16);
}

// Feature K-slot pairing (A[k]*B[k] summed by MFMA, K=16 of 32x32x16):
//  k0-2 : (-2p)_h * q_h      k3-5 : (-2p)_l * q_h     k6-8 : (-2p)_h * q_l
//  k9-10: p2_h,p2_l * 1      k11-12: 1 * q2_h,q2_l    k13-15: 0
// => D[m,n] = |p|^2 + |q|^2 - 2 p.q  (drops only (-2p)_l*q_l ~ 2^-18)
// Features are computed on the fly from raw floats (prep kernel fused away).
//
// Block = (256 rows of cloud[dir]) x (2048-col chunk of cloud[1-dir]) x
// (batch,dir). Grid (32,4,8) = 1024 blocks = 4/CU. 4 waves x 64 rows
// (2 MFMA row-tiles). Cols staged in 2 phases of 1024 (32 KB LDS), features
// computed during staging. Inner loop: 1 ds_read_b128 + 2 MFMA + 32
// independent fmin. Epilogue: LDS-transpose fold, plain partial-min store
// (no atomics, no init, slot owned uniquely by this block).
// 32x32x16 layouts: A row=lane&31, k=(lane>>5)*8+j; B col=lane&31, same k.
// C/D: col=lane&31, row=(r&3)+8*(r>>2)+4*(lane>>5)   [HW-verified mapping]
__global__ __launch_bounds__(256, 4) void chamfer_main_kernel(
    const float* __restrict__ tpl, const float* __restrict__ src,
    float* __restrict__ partials)
{
    // Union LDS: staging (2*1024*8 shorts = 32 KB) / epilogue (4*64*33 f32)
    __shared__ __align__(16) unsigned char smem[4 * 64 * 33 * 4];
    unsigned short* sB = (unsigned short*)smem;
    float* sEp = (float*)smem;

    const int aSlab = blockIdx.x;        // 0..31 (256 rows)
    const int bChnk = blockIdx.y;        // 0..3  (2048 cols)
    const int dir   = blockIdx.z & 1;    // 0: tpl->src, 1: src->tpl
    const int batch = blockIdx.z >> 1;   // 0..3

    const int t    = threadIdx.x;
    const int w    = t >> 6;             // wave 0..3
    const int lane = t & 63;
    const int col  = lane & 31;
    const int half = lane >> 5;          // k-half (k0-7 / k8-15)

    const float* Acloud = (dir ? src : tpl) + (size_t)batch * NPTS * 3;
    const float* Bcloud = (dir ? tpl : src) + (size_t)batch * NPTS * 3;

    const short ONE = (short)0x3F80;     // bf16 1.0

    // --- A fragments computed from raw floats (2 points per lane) ---
    bf16x8 afr[2];
#pragma unroll
    for (int a = 0; a < 2; ++a) {
        const float* p = Acloud + (size_t)(aSlab * 256 + w * 64 + a * 32 + col) * 3;
        const float x = p[0], y = p[1], z = p[2];
        const float n2 = fmaf(x, x, fmaf(y, y, z * z));
        const unsigned short n2h = bf16rn(n2);
        const unsigned short n2l = bf16rn(n2 - bf2f(n2h));
        const float mx = -2.0f * x, my = -2.0f * y, mz = -2.0f * z;
        const unsigned short ahx = bf16rn(mx), ahy = bf16rn(my), ahz = bf16rn(mz);
        const unsigned short alx = bf16rn(mx - bf2f(ahx));
        const unsigned short aly = bf16rn(my - bf2f(ahy));
        const unsigned short alz = bf16rn(mz - bf2f(ahz));
        const bf16x8 f0 = {(short)ahx, (short)ahy, (short)ahz, (short)alx,
                           (short)aly, (short)alz, (short)ahx, (short)ahy};
        const bf16x8 f1 = {(short)ahz, (short)n2h, (short)n2l, ONE, ONE, 0, 0, 0};
        afr[a] = half ? f1 : f0;
    }

    float vmin[2][16];
#pragma unroll
    for (int a = 0; a < 2; ++a)
#pragma unroll
        for (int r = 0; r < 16; ++r) vmin[a][r] = 3.0e38f;

    const f32x16 ZERO = (f32x16)(0.0f);

    // Two staging phases of 1024 cols each; features computed inline.
#pragma unroll 1
    for (int phase = 0; phase < 2; ++phase) {
        {
            const float4* g4 =
                (const float4*)(Bcloud + (size_t)(bChnk * 2048 + phase * 1024) * 3);
            // Thread t handles points 4t..4t+3 (12 floats = 3 contiguous float4).
            const float4 v0 = g4[t * 3 + 0];
            const float4 v1 = g4[t * 3 + 1];
            const float4 v2 = g4[t * 3 + 2];
            const float px[4] = {v0.x, v0.w, v1.z, v2.y};
            const float py[4] = {v0.y, v1.x, v1.w, v2.z};
            const float pz[4] = {v0.z, v1.y, v2.x, v2.w};
#pragma unroll
            for (int i = 0; i < 4; ++i) {
                const int pt = t * 4 + i;
                const float x = px[i], y = py[i], z = pz[i];
                const float n2 = fmaf(x, x, fmaf(y, y, z * z));
                const unsigned short n2h = bf16rn(n2);
                const unsigned short n2l = bf16rn(n2 - bf2f(n2h));
                const unsigned short hx = bf16rn(x), hy = bf16rn(y), hz = bf16rn(z);
                const unsigned short lx = bf16rn(x - bf2f(hx));
                const unsigned short ly = bf16rn(y - bf2f(hy));
                const unsigned short lz = bf16rn(z - bf2f(hz));
                const bf16x8 h0 = {(short)hx, (short)hy, (short)hz, (short)hx,
                                   (short)hy, (short)hz, (short)lx, (short)ly};
                const bf16x8 h1 = {(short)lz, ONE, ONE, (short)n2h, (short)n2l, 0, 0, 0};
                *(bf16x8*)&sB[((size_t)(0 * 1024 + pt)) * 8] = h0;
                *(bf16x8*)&sB[((size_t)(1 * 1024 + pt)) * 8] = h1;
            }
        }
        __syncthreads();

        const unsigned short* sBh = &sB[(size_t)(half * 1024) * 8];
#pragma unroll 8
        for (int bt = 0; bt < 32; ++bt) {
            const bf16x8 bfr = *(const bf16x8*)&sBh[((size_t)(bt * 32 + col)) * 8];
#pragma unroll
            for (int a = 0; a < 2; ++a) {
                const f32x16 d = __builtin_amdgcn_mfma_f32_32x32x16_bf16(afr[a], bfr, ZERO, 0, 0, 0);
#pragma unroll
                for (int r = 0; r < 16; ++r) vmin[a][r] = fminf(vmin[a][r], d[r]);
            }
        }
        __syncthreads();   // all waves done with sB before restage / epilogue reuse
    }

    // Epilogue: LDS-transpose fold. Region per wave: 64 lanes x 33 floats (pad).
    float* ep = sEp + (size_t)w * (64 * 33);
#pragma unroll
    for (int a = 0; a < 2; ++a)
#pragma unroll
        for (int r = 0; r < 16; ++r)
            ep[lane * 33 + a * 16 + r] = vmin[a][r];
    __syncthreads();

    // Lane owns row R = lane (within this wave's 64 rows).
    const int a_   = lane >> 5;
    const int rit  = lane & 31;
    const int hsrc = (rit >> 2) & 1;
    const int r_   = (rit & 3) | (((rit >> 3) & 3) << 2);
    const float* src0 = ep + (size_t)(hsrc * 32) * 33 + (a_ * 16 + r_);

    float m = 3.0e38f;
#pragma unroll
    for (int c = 0; c < 32; ++c)
        m = fminf(m, src0[c * 33]);

    // Unique slot per (row, bChnk): plain store, coalesced, no init needed.
    const int row = dir * CLOUD_PTS + batch * NPTS + aSlab * 256 + w * 64 + lane;
    partials[(size_t)bChnk * TOTAL_ROWS + row] = m;
}

// Min the NCHUNK partials per row, sqrt, per-block deterministic sums.
__global__ __launch_bounds__(256) void reduce_rows_kernel(
    const float* __restrict__ partials, float* __restrict__ blockSums)
{
    const int gid = blockIdx.x * 256 + threadIdx.x;
    float m = partials[gid];
#pragma unroll
    for (int c = 1; c < NCHUNK; ++c)
        m = fminf(m, partials[(size_t)c * TOTAL_ROWS + gid]);
    float d = sqrtf(fmaxf(m, 1e-12f));
#pragma unroll
    for (int off = 32; off; off >>= 1) d += __shfl_down(d, off);
    __shared__ float wsum[4];
    const int wave = threadIdx.x >> 6, lane = threadIdx.x & 63;
    if (lane == 0) wsum[wave] = d;
    __syncthreads();
    if (threadIdx.x == 0)
        blockSums[blockIdx.x] = (wsum[0] + wsum[1]) + (wsum[2] + wsum[3]);
}

__global__ __launch_bounds__(256) void final_kernel(
    const float* __restrict__ blockSums, float* __restrict__ out)
{
    float d = blockSums[threadIdx.x];
#pragma unroll
    for (int off = 32; off; off >>= 1) d += __shfl_down(d, off);
    __shared__ float wsum[4];
    const int wave = threadIdx.x >> 6, lane = threadIdx.x & 63;
    if (lane == 0) wsum[wave] = d;
    __syncthreads();
    if (threadIdx.x == 0) {
        const float total = (wsum[0] + wsum[1]) + (wsum[2] + wsum[3]);
        out[0] = total / (float)(BATCH * NPTS);
    }
}

extern "C" void kernel_launch(void* const* d_in, const int* in_sizes, int n_in,
                              void* d_out, int out_size, void* d_ws, size_t ws_size,
                              hipStream_t stream) {
    const float* tpl = (const float*)d_in[0];
    const float* src = (const float*)d_in[1];
    float* out = (float*)d_out;

    float* partials  = (float*)d_ws;                       // 4 * 65536 floats = 1 MB
    float* blockSums = partials + (size_t)NCHUNK * TOTAL_ROWS;

    dim3 grid(NPTS / 256, NCHUNK, 2 * BATCH);   // (32, 4, 8) = 1024 blocks
    chamfer_main_kernel<<<grid, 256, 0, stream>>>(tpl, src, partials);

    reduce_rows_kernel<<<TOTAL_ROWS / 256, 256, 0, stream>>>(partials, blockSums);
    final_kernel<<<1, 256, 0, stream>>>(blockSums, out);
}